// Round 11
// baseline (123.163 us; speedup 1.0000x reference)
//
#include <hip/hip_runtime.h>
#include <hip/hip_bf16.h>

// Problem constants
#define NB 32      // batch
#define NC 8       // channels
#define NL 512     // length
#define NS 63      // scales
#define NK 1009    // max wavelet kernel length (odd)
#define NPAD 504   // (NK-1)/2
#define ND 512     // d_model
#define NCT 512    // total channels after concat = C*(1+S)
#define NROWS 514  // Apad rows per batch (circular-padded)

typedef __attribute__((ext_vector_type(4))) float f32x4;
typedef __attribute__((ext_vector_type(8))) short short8;
typedef __attribute__((ext_vector_type(4))) short short4v;

// Workspace layout (bytes)
#define APAD_BYTES (NB * NROWS * NL * 2)   // 16,842,752  bf16 [B][514][512]
#define WB_BYTES   (3 * ND * NL * 2)       //  1,572,864  bf16 [3][512][512]

typedef const __attribute__((address_space(1))) unsigned int* gp1_t;
typedef __attribute__((address_space(3))) unsigned int* lp3_t;
__device__ __forceinline__ void gload_lds16(const void* g, void* l) {
  __builtin_amdgcn_global_load_lds((gp1_t)g, (lp3_t)l, 16, 0, 0);
}

__device__ __forceinline__ unsigned short bf16_bits(float v) {
  return __builtin_bit_cast(unsigned short, __float2bfloat16(v));
}

#define WAITVM(N) asm volatile("s_waitcnt vmcnt(" #N ")" ::: "memory")
#define FENCE() asm volatile("" ::: "memory")
#define BAR() __builtin_amdgcn_s_barrier()

// ---------------------------------------------------------------------------
// Kernel 1: prep — Wb[k][o][l] = bf16(tw[o][l][k]); bankB[s][k] zero-padded.
// ---------------------------------------------------------------------------
__global__ __launch_bounds__(256) void prep_kernel(
    const float* __restrict__ bank, const float* __restrict__ tw,
    __hip_bfloat16* __restrict__ Wb, __hip_bfloat16* __restrict__ bankB) {
  const int idx = blockIdx.x * 256 + threadIdx.x;   // 65536 threads

  {
    int i0 = idx * 4;
    const float4* t4 = (const float4*)(tw + (size_t)i0 * 3);
    float4 a = t4[0], bq = t4[1], c4 = t4[2];
    ushort4 w0 = make_ushort4(bf16_bits(a.x), bf16_bits(a.w), bf16_bits(bq.z), bf16_bits(c4.y));
    ushort4 w1 = make_ushort4(bf16_bits(a.y), bf16_bits(bq.x), bf16_bits(bq.w), bf16_bits(c4.z));
    ushort4 w2 = make_ushort4(bf16_bits(a.z), bf16_bits(bq.y), bf16_bits(c4.x), bf16_bits(c4.w));
    *(ushort4*)(Wb + 0 * ND * NL + i0) = w0;
    *(ushort4*)(Wb + 1 * ND * NL + i0) = w1;
    *(ushort4*)(Wb + 2 * ND * NL + i0) = w2;
  }
  {
    int s = idx >> 10, k = idx & 1023;
    float v = (s < NS && k < NK) ? bank[s * NK + k] : 0.f;
    bankB[idx] = __float2bfloat16(v);
  }
}

// ---------------------------------------------------------------------------
// Kernel 2: cwt via MFMA (unchanged — best measured config).
// Block = (bc, h): h=0 handles scale-blocks {0,3}, h=1 handles {1,2}.
// ---------------------------------------------------------------------------
#define CPY_STRIDE 3088   // 1536*2 + 16 pad

__global__ __launch_bounds__(512) void cwt_kernel(
    const float* __restrict__ x, const __hip_bfloat16* __restrict__ bankB,
    __hip_bfloat16* __restrict__ Apad) {
  __shared__ char smem[8 * 8192 + 4 * CPY_STRIDE];  // 77,888 B
  char* bankS = smem;
  char* cpy = smem + 8 * 8192;

  const int tid = threadIdx.x;
  const int gid = blockIdx.x;
  const int bc = gid >> 1, h = gid & 1;
  const int b = bc >> 3, c = bc & 7;
  const int w = tid >> 6, l = tid & 63;
  const int hi = l >> 4, li = l & 15;
  const int ma = h ? 1 : 0, mb = h ? 2 : 3;   // scale-blocks handled

  const float* xrow = x + bc * NL;

  if (h == 0) {
    __hip_bfloat16 v = __float2bfloat16(xrow[tid & 511]);
    if (tid < 512) {
      Apad[((size_t)(b * NROWS) + 1 + c) * NL + tid] = v;
      if (c == 0) Apad[((size_t)(b * NROWS) + 513) * NL + tid] = v;
    }
  }

  for (int i = 0; i < 6; ++i) {
    int p = tid + i * 512;
    int r_ = p / 768, pe = p - r_ * 768;
    int e0 = 2 * pe;
    int i0 = e0 + r_;
    float xa = (i0 >= NPAD && i0 < NPAD + NL) ? xrow[i0 - NPAD] : 0.f;
    float xb = (i0 + 1 >= NPAD && i0 + 1 < NPAD + NL) ? xrow[i0 + 1 - NPAD] : 0.f;
    float xc = (i0 + 2 >= NPAD && i0 + 2 < NPAD + NL) ? xrow[i0 + 2 - NPAD] : 0.f;
    unsigned short u0 = bf16_bits(xb - xa);
    unsigned short u1 = bf16_bits(xc - xb);
    *(unsigned int*)(cpy + r_ * CPY_STRIDE + e0 * 2) = (unsigned)u0 | ((unsigned)u1 << 16);
  }

#define STAGE(kt)                                                             \
  {                                                                           \
    int s_ = tid >> 4, rb = tid & 15;                                         \
    int j = (s_ < 16) ? (ma * 16 + s_) : (mb * 16 + (s_ - 16));               \
    int srcc = rb ^ (s_ & 7);                                                 \
    gload_lds16(bankB + j * 1024 + (kt) * 128 + srcc * 8,                     \
                bankS + (kt) * 8192 + tid * 16);                              \
  }

#define CCOMP(kt, A0, A1)                                                      \
  {                                                                            \
    _Pragma("unroll") for (int ksl = 0; ksl < 4; ++ksl) {                      \
      short8 bv[4];                                                            \
      _Pragma("unroll") for (int n = 0; n < 4; ++n) {                          \
        int t = tbase + n * 16 + li;                                           \
        int e = t - r + (kt) * 128 + ksl * 32 + hi * 8;                        \
        const char* pc = cpy + r * CPY_STRIDE + e * 2;                         \
        short4v lo = *(const short4v*)pc;                                      \
        short4v hh = *(const short4v*)(pc + 8);                                \
        short8 f;                                                              \
        f[0] = lo[0]; f[1] = lo[1]; f[2] = lo[2]; f[3] = lo[3];                \
        f[4] = hh[0]; f[5] = hh[1]; f[6] = hh[2]; f[7] = hh[3];                \
        bv[n] = f;                                                             \
      }                                                                        \
      if (A0) {                                                                \
        int lrow = li;                                                         \
        int chunk = (ksl * 4 + hi) ^ (lrow & 7);                               \
        short8 av = *(const short8*)(bankS + (kt) * 8192 + lrow * 256 + chunk * 16); \
        _Pragma("unroll") for (int n = 0; n < 4; ++n)                          \
          acc[0][n] = __builtin_amdgcn_mfma_f32_16x16x32_bf16(av, bv[n],       \
                                                              acc[0][n], 0, 0, 0); \
      }                                                                        \
      if (A1) {                                                                \
        int lrow = 16 + li;                                                    \
        int chunk = (ksl * 4 + hi) ^ (lrow & 7);                               \
        short8 av = *(const short8*)(bankS + (kt) * 8192 + lrow * 256 + chunk * 16); \
        _Pragma("unroll") for (int n = 0; n < 4; ++n)                          \
          acc[1][n] = __builtin_amdgcn_mfma_f32_16x16x32_bf16(av, bv[n],       \
                                                              acc[1][n], 0, 0, 0); \
      }                                                                        \
    }                                                                          \
  }

  f32x4 acc[2][4] = {};
  const int r = l & 3;
  const int tbase = w * 64;

  if (h == 0) {
    STAGE(0); STAGE(1); STAGE(2); STAGE(3);
    STAGE(4); STAGE(5); STAGE(6); STAGE(7);
    asm volatile("s_waitcnt vmcnt(7) lgkmcnt(0)" ::: "memory");
    BAR(); FENCE(); CCOMP(0, 0, 1);
    WAITVM(6); BAR(); FENCE(); CCOMP(1, 0, 1);
    WAITVM(5); BAR(); FENCE(); CCOMP(2, 1, 1);
    WAITVM(4); BAR(); FENCE(); CCOMP(3, 1, 1);
    WAITVM(3); BAR(); FENCE(); CCOMP(4, 1, 1);
    WAITVM(2); BAR(); FENCE(); CCOMP(5, 0, 1);
    WAITVM(1); BAR(); FENCE(); CCOMP(6, 0, 1);
    WAITVM(0); BAR(); FENCE(); CCOMP(7, 0, 1);
  } else {
    STAGE(0); STAGE(1); STAGE(2); STAGE(3);
    STAGE(4); STAGE(5); STAGE(6);           // tile 7 unused by m1,m2
    asm volatile("s_waitcnt vmcnt(6) lgkmcnt(0)" ::: "memory");
    BAR(); FENCE(); CCOMP(0, 0, 1);
    WAITVM(5); BAR(); FENCE(); CCOMP(1, 1, 1);
    WAITVM(4); BAR(); FENCE(); CCOMP(2, 1, 1);
    WAITVM(3); BAR(); FENCE(); CCOMP(3, 1, 1);
    WAITVM(2); BAR(); FENCE(); CCOMP(4, 1, 1);
    WAITVM(1); BAR(); FENCE(); CCOMP(5, 1, 1);
    WAITVM(0); BAR(); FENCE(); CCOMP(6, 0, 1);
  }

#pragma unroll
  for (int mm = 0; mm < 2; ++mm) {
    const int mblk = mm ? mb : ma;
#pragma unroll
    for (int rg = 0; rg < 4; ++rg) {
      int jg = mblk * 16 + hi * 4 + rg;
      if (jg >= NS) continue;
      int ch = 8 + c * NS + jg;
      size_t rowbase = ((size_t)(b * NROWS) + 1 + ch) * NL;
#pragma unroll
      for (int n = 0; n < 4; ++n) {
        int t = tbase + n * 16 + li;
        float d = fabsf(acc[mm][n][rg]);
        __hip_bfloat16 hv = __float2bfloat16(d);
        bool lastgrp = (w == 7 && n == 3);
        bool skip = lastgrp && (li == 15);
        bool dup = lastgrp && (li == 14);
        if (!skip) Apad[rowbase + t] = hv;
        if (dup) Apad[rowbase + 511] = hv;
        if (ch == NCT - 1) {
          size_t wrapbase = (size_t)(b * NROWS) * NL;
          if (!skip) Apad[wrapbase + t] = hv;
          if (dup) Apad[wrapbase + 511] = hv;
        }
      }
    }
  }
#undef STAGE
#undef CCOMP
}

// ---------------------------------------------------------------------------
// Kernel 3: gemm — ONE WAVE PER 64x64 OUTPUT TILE, no LDS, no barriers.
// Unified GEMM view: M = 32*512 = 16384, N = 512, K = 1536 (3 kap x 512 l).
// Both A and B fragments stream global -> VGPR (A is L2-hot: re-read x8 per
// XCD-local slab; Wb is 1.5MB, read by all). 2048 blocks x 64 thr = 8 wv/CU.
// Depth-2 software pipeline with 3 static register sets; NO inline waits —
// the compiler's per-use vmcnt insertion handles a pure dataflow stream.
// XCD decode: XCD x owns Mblks [32x, 32x+32) (2 batches: A 1.05MB + Wb 1.5MB
// fits 4MB L2), all 8 o-slabs.
// ---------------------------------------------------------------------------
__global__ __launch_bounds__(64) void gemm_kernel(
    const __hip_bfloat16* __restrict__ Ap, const __hip_bfloat16* __restrict__ Wb,
    float* __restrict__ out) {
  const int lane = threadIdx.x;
  const int row_in = lane & 15, hi = lane >> 4;

  const int gid = blockIdx.x;               // 0..2047
  const int mblk = (gid & 7) * 32 + ((gid >> 3) & 31);  // 0..255
  const int nblk = gid >> 8;                             // 0..7
  const int b = mblk >> 3;
  const int p0 = (mblk & 7) * 64;
  const int o0 = nblk * 64;

  // lane-invariant bases (include row_in and hi offsets)
  const __hip_bfloat16* apBase =
      Ap + ((size_t)(b * NROWS) + p0 + row_in) * NL + hi * 8;
  const __hip_bfloat16* wbBase =
      Wb + ((size_t)o0 + row_in) * NL + hi * 8;

#define LOADS(kk, A, B)                                                        \
  {                                                                            \
    const int kap_ = (kk) >> 4;                                                \
    const int l0_ = ((kk) & 15) << 5;                                          \
    _Pragma("unroll") for (int m = 0; m < 4; ++m)                              \
      A[m] = *(const short8*)(apBase + (size_t)(kap_ + m * 16) * NL + l0_);    \
    _Pragma("unroll") for (int n = 0; n < 4; ++n)                              \
      B[n] = *(const short8*)(wbBase + (size_t)(kap_ * ND + n * 16) * NL + l0_); \
  }

#define COMP(A, B)                                                             \
  {                                                                            \
    _Pragma("unroll") for (int m = 0; m < 4; ++m)                              \
      _Pragma("unroll") for (int n = 0; n < 4; ++n)                            \
        acc[m][n] = __builtin_amdgcn_mfma_f32_16x16x32_bf16(A[m], B[n],        \
                                                            acc[m][n], 0, 0, 0); \
  }

  f32x4 acc[4][4] = {};
  short8 a0[4], b0[4], a1[4], b1[4], a2[4], b2[4];

  LOADS(0, a0, b0);
  LOADS(1, a1, b1);

  // 15 full groups of 3 steps (kg = 0,3,...,42), fully unrolled, all literal
#define GRP(kg)                                                                \
  LOADS((kg) + 2, a2, b2); COMP(a0, b0);                                       \
  LOADS((kg) + 3, a0, b0); COMP(a1, b1);                                       \
  LOADS((kg) + 4, a1, b1); COMP(a2, b2);

  GRP(0) GRP(3) GRP(6) GRP(9) GRP(12)
  GRP(15) GRP(18) GRP(21) GRP(24) GRP(27)
  GRP(30) GRP(33) GRP(36) GRP(39) GRP(42)
  // tail: kg = 45: steps 45,46,47 (loads for 47 already pending via GRP(42)+2)
  LOADS(47, a2, b2); COMP(a0, b0);
  COMP(a1, b1);
  COMP(a2, b2);
#undef GRP
#undef LOADS
#undef COMP

  // epilogue: out[b][p][o], p = p0 + m*16 + hi*4 + rg, o = o0 + n*16 + row_in
#pragma unroll
  for (int m = 0; m < 4; ++m) {
    const int p = p0 + m * 16 + hi * 4;
#pragma unroll
    for (int n = 0; n < 4; ++n) {
      const int o = o0 + n * 16 + row_in;
#pragma unroll
      for (int r = 0; r < 4; ++r)
        out[(size_t)((b * NCT) + p + r) * ND + o] = acc[m][n][r];
    }
  }
}

// ---------------------------------------------------------------------------
extern "C" void kernel_launch(void* const* d_in, const int* in_sizes, int n_in,
                              void* d_out, int out_size, void* d_ws, size_t ws_size,
                              hipStream_t stream) {
  const float* x = (const float*)d_in[0];
  const float* bank = (const float*)d_in[1];
  const float* tw = (const float*)d_in[2];
  float* out = (float*)d_out;

  char* ws = (char*)d_ws;
  __hip_bfloat16* Apad = (__hip_bfloat16*)ws;
  __hip_bfloat16* Wb = (__hip_bfloat16*)(ws + APAD_BYTES);
  __hip_bfloat16* bankB = (__hip_bfloat16*)(ws + APAD_BYTES + WB_BYTES);

  prep_kernel<<<256, 256, 0, stream>>>(bank, tw, Wb, bankB);
  cwt_kernel<<<512, 512, 0, stream>>>(x, bankB, Apad);
  gemm_kernel<<<2048, 64, 0, stream>>>(Apad, Wb, out);
}

// Round 12
// 72.709 us; speedup vs baseline: 1.6939x; 1.6939x over previous
//
#include <hip/hip_runtime.h>
#include <hip/hip_bf16.h>

// Problem constants
#define NB 32      // batch
#define NC 8       // channels
#define NL 512     // length
#define NS 63      // scales
#define NK 1009    // max wavelet kernel length (odd)
#define NPAD 504   // (NK-1)/2
#define ND 512     // d_model
#define NCT 512    // total channels after concat = C*(1+S)
#define NROWS 514  // Apad rows per batch (circular-padded)

typedef __attribute__((ext_vector_type(4))) float f32x4;
typedef __attribute__((ext_vector_type(8))) short short8;
typedef __attribute__((ext_vector_type(4))) short short4v;

// Workspace layout (bytes)
#define APAD_BYTES (NB * NROWS * NL * 2)   // 16,842,752  bf16 [B][514][512]
#define WB_BYTES   (3 * ND * NL * 2)       //  1,572,864  bf16 [3][512][512]

typedef const __attribute__((address_space(1))) unsigned int* gp1_t;
typedef __attribute__((address_space(3))) unsigned int* lp3_t;
__device__ __forceinline__ void gload_lds16(const void* g, void* l) {
  __builtin_amdgcn_global_load_lds((gp1_t)g, (lp3_t)l, 16, 0, 0);
}

__device__ __forceinline__ unsigned short bf16_bits(float v) {
  return __builtin_bit_cast(unsigned short, __float2bfloat16(v));
}

#define WAITVM(N) asm volatile("s_waitcnt vmcnt(" #N ")" ::: "memory")
#define FENCE() asm volatile("" ::: "memory")
#define BAR() __builtin_amdgcn_s_barrier()

// ---------------------------------------------------------------------------
// Kernel 1: prep — Wb[k][o][l] = bf16(tw[o][l][k]); bankB[s][k] zero-padded.
// ---------------------------------------------------------------------------
__global__ __launch_bounds__(256) void prep_kernel(
    const float* __restrict__ bank, const float* __restrict__ tw,
    __hip_bfloat16* __restrict__ Wb, __hip_bfloat16* __restrict__ bankB) {
  const int idx = blockIdx.x * 256 + threadIdx.x;   // 65536 threads

  {
    int i0 = idx * 4;
    const float4* t4 = (const float4*)(tw + (size_t)i0 * 3);
    float4 a = t4[0], bq = t4[1], c4 = t4[2];
    ushort4 w0 = make_ushort4(bf16_bits(a.x), bf16_bits(a.w), bf16_bits(bq.z), bf16_bits(c4.y));
    ushort4 w1 = make_ushort4(bf16_bits(a.y), bf16_bits(bq.x), bf16_bits(bq.w), bf16_bits(c4.z));
    ushort4 w2 = make_ushort4(bf16_bits(a.z), bf16_bits(bq.y), bf16_bits(c4.x), bf16_bits(c4.w));
    *(ushort4*)(Wb + 0 * ND * NL + i0) = w0;
    *(ushort4*)(Wb + 1 * ND * NL + i0) = w1;
    *(ushort4*)(Wb + 2 * ND * NL + i0) = w2;
  }
  {
    int s = idx >> 10, k = idx & 1023;
    float v = (s < NS && k < NK) ? bank[s * NK + k] : 0.f;
    bankB[idx] = __float2bfloat16(v);
  }
}

// ---------------------------------------------------------------------------
// Kernel 2: cwt via MFMA (unchanged — best measured config).
// Block = (bc, h): h=0 handles scale-blocks {0,3}, h=1 handles {1,2}.
// ---------------------------------------------------------------------------
#define CPY_STRIDE 3088   // 1536*2 + 16 pad

__global__ __launch_bounds__(512) void cwt_kernel(
    const float* __restrict__ x, const __hip_bfloat16* __restrict__ bankB,
    __hip_bfloat16* __restrict__ Apad) {
  __shared__ char smem[8 * 8192 + 4 * CPY_STRIDE];  // 77,888 B
  char* bankS = smem;
  char* cpy = smem + 8 * 8192;

  const int tid = threadIdx.x;
  const int gid = blockIdx.x;
  const int bc = gid >> 1, h = gid & 1;
  const int b = bc >> 3, c = bc & 7;
  const int w = tid >> 6, l = tid & 63;
  const int hi = l >> 4, li = l & 15;
  const int ma = h ? 1 : 0, mb = h ? 2 : 3;   // scale-blocks handled

  const float* xrow = x + bc * NL;

  if (h == 0) {
    __hip_bfloat16 v = __float2bfloat16(xrow[tid & 511]);
    if (tid < 512) {
      Apad[((size_t)(b * NROWS) + 1 + c) * NL + tid] = v;
      if (c == 0) Apad[((size_t)(b * NROWS) + 513) * NL + tid] = v;
    }
  }

  for (int i = 0; i < 6; ++i) {
    int p = tid + i * 512;
    int r_ = p / 768, pe = p - r_ * 768;
    int e0 = 2 * pe;
    int i0 = e0 + r_;
    float xa = (i0 >= NPAD && i0 < NPAD + NL) ? xrow[i0 - NPAD] : 0.f;
    float xb = (i0 + 1 >= NPAD && i0 + 1 < NPAD + NL) ? xrow[i0 + 1 - NPAD] : 0.f;
    float xc = (i0 + 2 >= NPAD && i0 + 2 < NPAD + NL) ? xrow[i0 + 2 - NPAD] : 0.f;
    unsigned short u0 = bf16_bits(xb - xa);
    unsigned short u1 = bf16_bits(xc - xb);
    *(unsigned int*)(cpy + r_ * CPY_STRIDE + e0 * 2) = (unsigned)u0 | ((unsigned)u1 << 16);
  }

#define STAGE(kt)                                                             \
  {                                                                           \
    int s_ = tid >> 4, rb = tid & 15;                                         \
    int j = (s_ < 16) ? (ma * 16 + s_) : (mb * 16 + (s_ - 16));               \
    int srcc = rb ^ (s_ & 7);                                                 \
    gload_lds16(bankB + j * 1024 + (kt) * 128 + srcc * 8,                     \
                bankS + (kt) * 8192 + tid * 16);                              \
  }

#define CCOMP(kt, A0, A1)                                                      \
  {                                                                            \
    _Pragma("unroll") for (int ksl = 0; ksl < 4; ++ksl) {                      \
      short8 bv[4];                                                            \
      _Pragma("unroll") for (int n = 0; n < 4; ++n) {                          \
        int t = tbase + n * 16 + li;                                           \
        int e = t - r + (kt) * 128 + ksl * 32 + hi * 8;                        \
        const char* pc = cpy + r * CPY_STRIDE + e * 2;                         \
        short4v lo = *(const short4v*)pc;                                      \
        short4v hh = *(const short4v*)(pc + 8);                                \
        short8 f;                                                              \
        f[0] = lo[0]; f[1] = lo[1]; f[2] = lo[2]; f[3] = lo[3];                \
        f[4] = hh[0]; f[5] = hh[1]; f[6] = hh[2]; f[7] = hh[3];                \
        bv[n] = f;                                                             \
      }                                                                        \
      if (A0) {                                                                \
        int lrow = li;                                                         \
        int chunk = (ksl * 4 + hi) ^ (lrow & 7);                               \
        short8 av = *(const short8*)(bankS + (kt) * 8192 + lrow * 256 + chunk * 16); \
        _Pragma("unroll") for (int n = 0; n < 4; ++n)                          \
          acc[0][n] = __builtin_amdgcn_mfma_f32_16x16x32_bf16(av, bv[n],       \
                                                              acc[0][n], 0, 0, 0); \
      }                                                                        \
      if (A1) {                                                                \
        int lrow = 16 + li;                                                    \
        int chunk = (ksl * 4 + hi) ^ (lrow & 7);                               \
        short8 av = *(const short8*)(bankS + (kt) * 8192 + lrow * 256 + chunk * 16); \
        _Pragma("unroll") for (int n = 0; n < 4; ++n)                          \
          acc[1][n] = __builtin_amdgcn_mfma_f32_16x16x32_bf16(av, bv[n],       \
                                                              acc[1][n], 0, 0, 0); \
      }                                                                        \
    }                                                                          \
  }

  f32x4 acc[2][4] = {};
  const int r = l & 3;
  const int tbase = w * 64;

  if (h == 0) {
    STAGE(0); STAGE(1); STAGE(2); STAGE(3);
    STAGE(4); STAGE(5); STAGE(6); STAGE(7);
    asm volatile("s_waitcnt vmcnt(7) lgkmcnt(0)" ::: "memory");
    BAR(); FENCE(); CCOMP(0, 0, 1);
    WAITVM(6); BAR(); FENCE(); CCOMP(1, 0, 1);
    WAITVM(5); BAR(); FENCE(); CCOMP(2, 1, 1);
    WAITVM(4); BAR(); FENCE(); CCOMP(3, 1, 1);
    WAITVM(3); BAR(); FENCE(); CCOMP(4, 1, 1);
    WAITVM(2); BAR(); FENCE(); CCOMP(5, 0, 1);
    WAITVM(1); BAR(); FENCE(); CCOMP(6, 0, 1);
    WAITVM(0); BAR(); FENCE(); CCOMP(7, 0, 1);
  } else {
    STAGE(0); STAGE(1); STAGE(2); STAGE(3);
    STAGE(4); STAGE(5); STAGE(6);           // tile 7 unused by m1,m2
    asm volatile("s_waitcnt vmcnt(6) lgkmcnt(0)" ::: "memory");
    BAR(); FENCE(); CCOMP(0, 0, 1);
    WAITVM(5); BAR(); FENCE(); CCOMP(1, 1, 1);
    WAITVM(4); BAR(); FENCE(); CCOMP(2, 1, 1);
    WAITVM(3); BAR(); FENCE(); CCOMP(3, 1, 1);
    WAITVM(2); BAR(); FENCE(); CCOMP(4, 1, 1);
    WAITVM(1); BAR(); FENCE(); CCOMP(5, 1, 1);
    WAITVM(0); BAR(); FENCE(); CCOMP(6, 0, 1);
  }

#pragma unroll
  for (int mm = 0; mm < 2; ++mm) {
    const int mblk = mm ? mb : ma;
#pragma unroll
    for (int rg = 0; rg < 4; ++rg) {
      int jg = mblk * 16 + hi * 4 + rg;
      if (jg >= NS) continue;
      int ch = 8 + c * NS + jg;
      size_t rowbase = ((size_t)(b * NROWS) + 1 + ch) * NL;
#pragma unroll
      for (int n = 0; n < 4; ++n) {
        int t = tbase + n * 16 + li;
        float d = fabsf(acc[mm][n][rg]);
        __hip_bfloat16 hv = __float2bfloat16(d);
        bool lastgrp = (w == 7 && n == 3);
        bool skip = lastgrp && (li == 15);
        bool dup = lastgrp && (li == 14);
        if (!skip) Apad[rowbase + t] = hv;
        if (dup) Apad[rowbase + 511] = hv;
        if (ch == NCT - 1) {
          size_t wrapbase = (size_t)(b * NROWS) * NL;
          if (!skip) Apad[wrapbase + t] = hv;
          if (dup) Apad[wrapbase + 511] = hv;
        }
      }
    }
  }
#undef STAGE
#undef CCOMP
}

// ---------------------------------------------------------------------------
// Kernel 3: gemm — out[b][p][o] = sum_{kap} sum_l Apad[b][p+kap][l]*Wb[kap][o][l]
// *** 128x64 tile -> 1024 blocks = 4 blocks/CU resident (the occupancy fix) ***
// 4 waves, wave owns 64x32 (m=4, n=2). 3-buffer, depth-2, WAITVM(6),
// two barriers/step (R5-proven hazard structure). LDS 36KB (4x fits 144KB).
// T2 source-swizzle; XCD decode: 8 o-variants of an A-slab share one XCD
// (16 mblks = 2 batches A 1.05MB + Wb 1.5MB < 4MB L2).
// ---------------------------------------------------------------------------
__global__ __launch_bounds__(256) void gemm_kernel(
    const __hip_bfloat16* __restrict__ Ap, const __hip_bfloat16* __restrict__ Wb,
    float* __restrict__ out) {
  __shared__ __hip_bfloat16 sA[3][128 * 32];   // 24 KB
  __shared__ __hip_bfloat16 sB[3][64 * 32];    // 12 KB

  const int tid = threadIdx.x;
  const int gid = blockIdx.x;                  // 0..1023
  const int j = gid >> 3;                      // 0..127
  const int mblk = (gid & 7) * 16 + (j & 15);  // 0..127 ; same-XCD A-slab
  const int nblk = j >> 4;                     // 0..7
  const int b = mblk >> 2;
  const int p0 = (mblk & 3) * 128;
  const int o0 = nblk * 64;

  const int w = tid >> 6, lane = tid & 63;
  const int wm = w >> 1, wn = w & 1;
  const int row_in = lane & 15, hi = lane >> 4;

  // A staging: 512 chunks of 16B (tid, tid+256); T2 source swizzle
  const int rA0 = tid >> 2, cgA0 = (tid & 3) ^ ((rA0 >> 1) & 3);
  const int ck1 = tid + 256;
  const int rA1 = ck1 >> 2, cgA1 = (ck1 & 3) ^ ((rA1 >> 1) & 3);
  // B staging: 256 chunks (64 rows x 4)
  const int rB = tid >> 2, cgB = (tid & 3) ^ ((rB >> 1) & 3);

#define GSTAGE(kk, bu)                                                         \
  {                                                                            \
    const int kap_ = (kk) >> 4;                                                \
    const int l0_ = ((kk) & 15) << 5;                                          \
    gload_lds16(Ap + ((b * NROWS + p0 + kap_ + rA0) * NL + l0_ + cgA0 * 8),    \
                &sA[bu][tid * 8]);                                             \
    gload_lds16(Ap + ((b * NROWS + p0 + kap_ + rA1) * NL + l0_ + cgA1 * 8),    \
                &sA[bu][ck1 * 8]);                                             \
    gload_lds16(Wb + ((kap_ * ND + o0 + rB) * NL + l0_ + cgB * 8),             \
                &sB[bu][tid * 8]);                                             \
  }

#define COMPUTE(bu)                                                            \
  {                                                                            \
    short8 av[4], bv[2];                                                       \
    _Pragma("unroll") for (int m = 0; m < 4; ++m) {                            \
      int row = wm * 64 + m * 16 + row_in;                                     \
      int slot = row * 4 + (hi ^ ((row >> 1) & 3));                            \
      av[m] = *(const short8*)(&sA[bu][slot * 8]);                             \
    }                                                                          \
    _Pragma("unroll") for (int n = 0; n < 2; ++n) {                            \
      int row = wn * 32 + n * 16 + row_in;                                     \
      int slot = row * 4 + (hi ^ ((row >> 1) & 3));                            \
      bv[n] = *(const short8*)(&sB[bu][slot * 8]);                             \
    }                                                                          \
    _Pragma("unroll") for (int m = 0; m < 4; ++m)                              \
      _Pragma("unroll") for (int n = 0; n < 2; ++n)                            \
        acc[m][n] = __builtin_amdgcn_mfma_f32_16x16x32_bf16(av[m], bv[n],      \
                                                            acc[m][n], 0, 0, 0); \
  }

#define STEP(kk, bu, bs)                                                       \
  GSTAGE((kk) + 2, bs); WAITVM(6); BAR(); FENCE(); COMPUTE(bu); FENCE(); BAR();

  f32x4 acc[4][2] = {};

  GSTAGE(0, 0); GSTAGE(1, 1);

  for (int g = 0; g < 15; ++g) {
    const int kk = g * 3;
    STEP(kk + 0, 0, 2);
    STEP(kk + 1, 1, 0);
    STEP(kk + 2, 2, 1);
  }
  // tail: kk = 45 (stage 47), 46, 47
  GSTAGE(47, 2); WAITVM(6); BAR(); FENCE(); COMPUTE(0); FENCE(); BAR();
  WAITVM(3); BAR(); FENCE(); COMPUTE(1); FENCE(); BAR();
  WAITVM(0); BAR(); FENCE(); COMPUTE(2);
#undef GSTAGE
#undef COMPUTE
#undef STEP

  // epilogue: p = p0 + wm*64 + m*16 + hi*4 + r ; o = o0 + wn*32 + n*16 + row_in
#pragma unroll
  for (int m = 0; m < 4; ++m) {
    const int p = p0 + wm * 64 + m * 16 + hi * 4;
#pragma unroll
    for (int n = 0; n < 2; ++n) {
      const int o = o0 + wn * 32 + n * 16 + row_in;
#pragma unroll
      for (int r = 0; r < 4; ++r)
        out[(size_t)((b * NCT) + p + r) * ND + o] = acc[m][n][r];
    }
  }
}

// ---------------------------------------------------------------------------
extern "C" void kernel_launch(void* const* d_in, const int* in_sizes, int n_in,
                              void* d_out, int out_size, void* d_ws, size_t ws_size,
                              hipStream_t stream) {
  const float* x = (const float*)d_in[0];
  const float* bank = (const float*)d_in[1];
  const float* tw = (const float*)d_in[2];
  float* out = (float*)d_out;

  char* ws = (char*)d_ws;
  __hip_bfloat16* Apad = (__hip_bfloat16*)ws;
  __hip_bfloat16* Wb = (__hip_bfloat16*)(ws + APAD_BYTES);
  __hip_bfloat16* bankB = (__hip_bfloat16*)(ws + APAD_BYTES + WB_BYTES);

  prep_kernel<<<256, 256, 0, stream>>>(bank, tw, Wb, bankB);
  cwt_kernel<<<512, 512, 0, stream>>>(x, bankB, Apad);
  gemm_kernel<<<1024, 256, 0, stream>>>(Apad, Wb, out);
}

// Round 13
// 60.515 us; speedup vs baseline: 2.0352x; 1.2015x over previous
//
#include <hip/hip_runtime.h>
#include <hip/hip_bf16.h>

// Problem constants
#define NB 32      // batch
#define NC 8       // channels
#define NL 512     // length
#define NS 63      // scales
#define NK 1009    // max wavelet kernel length (odd)
#define NPAD 504   // (NK-1)/2
#define ND 512     // d_model
#define NCT 512    // total channels after concat = C*(1+S)
#define NROWS 514  // Apad rows per batch (circular-padded)

typedef __attribute__((ext_vector_type(4))) float f32x4;
typedef __attribute__((ext_vector_type(8))) short short8;

// Workspace layout (bytes)
#define APAD_BYTES (NB * NROWS * NL * 2)   // 16,842,752  bf16 [B][514][512]
#define WB_BYTES   (3 * ND * NL * 2)       //  1,572,864  bf16 [3][512][512]

typedef const __attribute__((address_space(1))) unsigned int* gp1_t;
typedef __attribute__((address_space(3))) unsigned int* lp3_t;
__device__ __forceinline__ void gload_lds16(const void* g, void* l) {
  __builtin_amdgcn_global_load_lds((gp1_t)g, (lp3_t)l, 16, 0, 0);
}

__device__ __forceinline__ unsigned short bf16_bits(float v) {
  return __builtin_bit_cast(unsigned short, __float2bfloat16(v));
}

#define WAITVM(N) asm volatile("s_waitcnt vmcnt(" #N ")" ::: "memory")
#define FENCE() asm volatile("" ::: "memory")
#define BAR() __builtin_amdgcn_s_barrier()

// ---------------------------------------------------------------------------
// Kernel 1: prep — Wb[k][o][l] = bf16(tw[o][l][k]); bankB[s][k] zero-padded.
// ---------------------------------------------------------------------------
__global__ __launch_bounds__(256) void prep_kernel(
    const float* __restrict__ bank, const float* __restrict__ tw,
    __hip_bfloat16* __restrict__ Wb, __hip_bfloat16* __restrict__ bankB) {
  const int idx = blockIdx.x * 256 + threadIdx.x;   // 65536 threads

  {
    int i0 = idx * 4;
    const float4* t4 = (const float4*)(tw + (size_t)i0 * 3);
    float4 a = t4[0], bq = t4[1], c4 = t4[2];
    ushort4 w0 = make_ushort4(bf16_bits(a.x), bf16_bits(a.w), bf16_bits(bq.z), bf16_bits(c4.y));
    ushort4 w1 = make_ushort4(bf16_bits(a.y), bf16_bits(bq.x), bf16_bits(bq.w), bf16_bits(c4.z));
    ushort4 w2 = make_ushort4(bf16_bits(a.z), bf16_bits(bq.y), bf16_bits(c4.x), bf16_bits(c4.w));
    *(ushort4*)(Wb + 0 * ND * NL + i0) = w0;
    *(ushort4*)(Wb + 1 * ND * NL + i0) = w1;
    *(ushort4*)(Wb + 2 * ND * NL + i0) = w2;
  }
  {
    int s = idx >> 10, k = idx & 1023;
    float v = (s < NS && k < NK) ? bank[s * NK + k] : 0.f;
    bankB[idx] = __float2bfloat16(v);
  }
}

// ---------------------------------------------------------------------------
// Kernel 2: cwt via MFMA.  d[t][s] = | sum_k bank[s][k] * dx[t+k] |.
// One block per bc (8 waves over t, all 64 scales). Bank: 8 K-tiles staged
// upfront (128KB, XOR-swizzled source), counted-vmcnt ladder (bench-R6).
// dx: 8 shifted copies (r = lane&7, stride 3152 = 16x197) with +8 elem
// offset -> every bv fragment is ONE 16B-aligned ds_read_b128, 2 lanes per
// bank-quad per phase (conflict-free minimum). Zero-tile masks kept.
// ---------------------------------------------------------------------------
#define CPY8_STRIDE 3152   // 16*197, 197 odd -> quad spread across copies

__global__ __launch_bounds__(512) void cwt_kernel(
    const float* __restrict__ x, const __hip_bfloat16* __restrict__ bankB,
    __hip_bfloat16* __restrict__ Apad) {
  __shared__ __align__(16) char smem[8 * 16384 + 8 * CPY8_STRIDE];  // 156,288 B
  char* bankS = smem;
  char* cpy = smem + 8 * 16384;

  const int tid = threadIdx.x;
  const int bc = blockIdx.x;
  const int b = bc >> 3, c = bc & 7;
  const int w = tid >> 6, l = tid & 63;
  const int hi = l >> 4, li = l & 15;
  const int r8 = l & 7;

  const float* xrow = x + bc * NL;

  // x -> Apad row 1+c (and wrap row 513 from c==0)
  if (tid < 512) {
    __hip_bfloat16 v = __float2bfloat16(xrow[tid]);
    Apad[((size_t)(b * NROWS) + 1 + c) * NL + tid] = v;
    if (c == 0) Apad[((size_t)(b * NROWS) + 513) * NL + tid] = v;
  }

  // dx fill: 8 copies, cpy8[r][g] = bf16(dx[g - 8 + r]), g in [0, 1544)
  // (dx[i] = xpad[i+1] - xpad[i], zero outside; +8 offset keeps g >= 0)
  for (int i = 0; i < 13; ++i) {
    int p = tid + i * 512;               // 0..6655; need 8*772 = 6176
    if (p < 6176) {
      int r_ = p / 772;
      int pe = p - r_ * 772;
      int g0 = 2 * pe;                   // 0..1542
      int i0 = g0 - 8 + r_;              // dx index of first elem (may be <0)
      float xa = (i0 >= NPAD && i0 < NPAD + NL) ? xrow[i0 - NPAD] : 0.f;
      float xb = (i0 + 1 >= NPAD && i0 + 1 < NPAD + NL) ? xrow[i0 + 1 - NPAD] : 0.f;
      float xc = (i0 + 2 >= NPAD && i0 + 2 < NPAD + NL) ? xrow[i0 + 2 - NPAD] : 0.f;
      unsigned u = (unsigned)bf16_bits(xb - xa) | ((unsigned)bf16_bits(xc - xb) << 16);
      *(unsigned*)(cpy + r_ * CPY8_STRIDE + g0 * 2) = u;
    }
  }

#define STAGE(kt)                                                             \
  {                                                                           \
    for (int i = 0; i < 2; ++i) {                                             \
      int ck = tid + i * 512;                                                 \
      int s_ = ck >> 4, rb = ck & 15;                                         \
      int srcc = rb ^ (s_ & 7);                                               \
      gload_lds16(bankB + s_ * 1024 + (kt) * 128 + srcc * 8,                  \
                  bankS + (kt) * 16384 + ck * 16);                            \
    }                                                                         \
  }

#define AVMM(kt, ksl, m)                                                       \
  {                                                                            \
    int srow = (m) * 16 + li;                                                  \
    int chunk = ((ksl) * 4 + hi) ^ (srow & 7);                                 \
    short8 av = *(const short8*)(bankS + (kt) * 16384 + srow * 256 + chunk * 16); \
    _Pragma("unroll") for (int n = 0; n < 4; ++n)                              \
      acc[m][n] = __builtin_amdgcn_mfma_f32_16x16x32_bf16(av, bv[n],           \
                                                          acc[m][n], 0, 0, 0); \
  }

#define CCOMP(kt, M0, M1, M2, M3)                                              \
  {                                                                            \
    _Pragma("unroll") for (int ksl = 0; ksl < 4; ++ksl) {                      \
      short8 bv[4];                                                            \
      _Pragma("unroll") for (int n = 0; n < 4; ++n) {                          \
        int ebyte = 16 + 2 * (tbase + n * 16 + 8 * (li >> 3) +                 \
                              (kt) * 128 + ksl * 32 + 8 * hi);                 \
        bv[n] = *(const short8*)(cpy + r8 * CPY8_STRIDE + ebyte);              \
      }                                                                        \
      if (M0) AVMM(kt, ksl, 0);                                                \
      if (M1) AVMM(kt, ksl, 1);                                                \
      if (M2) AVMM(kt, ksl, 2);                                                \
      if (M3) AVMM(kt, ksl, 3);                                                \
    }                                                                          \
  }

  // issue ALL 8 tile stages (16 gload_lds in flight)
  STAGE(0); STAGE(1); STAGE(2); STAGE(3);
  STAGE(4); STAGE(5); STAGE(6); STAGE(7);

  f32x4 acc[4][4] = {};
  const int tbase = w * 64;

  // masks: m0 kt2-4, m1 kt1-5, m2 kt0-6, m3 all (exact zero supports)
  asm volatile("s_waitcnt vmcnt(14) lgkmcnt(0)" ::: "memory");
  BAR(); FENCE(); CCOMP(0, 0, 0, 1, 1);
  WAITVM(12); BAR(); FENCE(); CCOMP(1, 0, 1, 1, 1);
  WAITVM(10); BAR(); FENCE(); CCOMP(2, 1, 1, 1, 1);
  WAITVM(8);  BAR(); FENCE(); CCOMP(3, 1, 1, 1, 1);
  WAITVM(6);  BAR(); FENCE(); CCOMP(4, 1, 1, 1, 1);
  WAITVM(4);  BAR(); FENCE(); CCOMP(5, 0, 1, 1, 1);
  WAITVM(2);  BAR(); FENCE(); CCOMP(6, 0, 0, 1, 1);
  WAITVM(0);  BAR(); FENCE(); CCOMP(7, 0, 0, 0, 1);

  // epilogue: d = |acc|; lane holds D[s=m*16+hi*4+rg][t=w*64+n*16+li]
#pragma unroll
  for (int m = 0; m < 4; ++m) {
#pragma unroll
    for (int rg = 0; rg < 4; ++rg) {
      int s = m * 16 + hi * 4 + rg;
      if (s >= NS) continue;
      int ch = 8 + c * NS + s;
      size_t rowbase = ((size_t)(b * NROWS) + 1 + ch) * NL;
#pragma unroll
      for (int n = 0; n < 4; ++n) {
        int t = tbase + n * 16 + li;
        float d = fabsf(acc[m][n][rg]);
        __hip_bfloat16 hv = __float2bfloat16(d);
        bool lastgrp = (w == 7 && n == 3);
        bool skip = lastgrp && (li == 15);     // t=511 slot invalid
        bool dup = lastgrp && (li == 14);      // t=510 also writes t=511
        if (!skip) Apad[rowbase + t] = hv;
        if (dup) Apad[rowbase + 511] = hv;
        if (ch == NCT - 1) {                   // wrap row 0 = feat channel 511
          size_t wrapbase = (size_t)(b * NROWS) * NL;
          if (!skip) Apad[wrapbase + t] = hv;
          if (dup) Apad[wrapbase + 511] = hv;
        }
      }
    }
  }
#undef STAGE
#undef AVMM
#undef CCOMP
}

// ---------------------------------------------------------------------------
// Kernel 3: gemm — EXACT bench-R6 configuration (measured-best ~38 us):
// 128x128 tile, BK=32, 4 LDS buffers, stage-2-ahead, counted vmcnt(8),
// ONE raw barrier per K-step; T2 source-swizzle; T1 XCD decode.
// ---------------------------------------------------------------------------
__global__ __launch_bounds__(256) void gemm_kernel(
    const __hip_bfloat16* __restrict__ Ap, const __hip_bfloat16* __restrict__ Wb,
    float* __restrict__ out) {
  __shared__ __hip_bfloat16 sA[4][128 * 32];
  __shared__ __hip_bfloat16 sB[4][128 * 32];

  const int tid = threadIdx.x;
  const int gid = blockIdx.x;          // 0..511
  const int q = gid >> 3;              // 0..63
  const int pid = (gid & 7) * 16 + (q >> 2);  // 0..127
  const int b = pid >> 2;
  const int p0 = (pid & 3) * 128;
  const int o0 = (q & 3) * 128;

  const int w = tid >> 6, lane = tid & 63;
  const int wm = w >> 1, wn = w & 1;
  const int row_in = lane & 15, hi = lane >> 4;

  const int r0 = tid >> 2, cg0 = (tid & 3) ^ ((r0 >> 1) & 3);
  const int ck1 = tid + 256;
  const int r1 = ck1 >> 2, cg1 = (ck1 & 3) ^ ((r1 >> 1) & 3);

#define GSTAGE(kk, bu)                                                         \
  {                                                                            \
    const int kap_ = (kk) >> 4;                                                \
    const int l0_ = ((kk) & 15) << 5;                                          \
    gload_lds16(Ap + ((b * NROWS + p0 + kap_ + r0) * NL + l0_ + cg0 * 8),      \
                &sA[bu][tid * 8]);                                             \
    gload_lds16(Ap + ((b * NROWS + p0 + kap_ + r1) * NL + l0_ + cg1 * 8),      \
                &sA[bu][ck1 * 8]);                                             \
    gload_lds16(Wb + ((kap_ * ND + o0 + r0) * NL + l0_ + cg0 * 8),             \
                &sB[bu][tid * 8]);                                             \
    gload_lds16(Wb + ((kap_ * ND + o0 + r1) * NL + l0_ + cg1 * 8),             \
                &sB[bu][ck1 * 8]);                                             \
  }

#define COMPUTE(bu)                                                            \
  {                                                                            \
    short8 av[4], bv[4];                                                       \
    _Pragma("unroll") for (int m = 0; m < 4; ++m) {                            \
      int row = wm * 64 + m * 16 + row_in;                                     \
      int slot = row * 4 + (hi ^ ((row >> 1) & 3));                            \
      av[m] = *(const short8*)(&sA[bu][slot * 8]);                             \
    }                                                                          \
    _Pragma("unroll") for (int n = 0; n < 4; ++n) {                            \
      int row = wn * 64 + n * 16 + row_in;                                     \
      int slot = row * 4 + (hi ^ ((row >> 1) & 3));                            \
      bv[n] = *(const short8*)(&sB[bu][slot * 8]);                             \
    }                                                                          \
    _Pragma("unroll") for (int m = 0; m < 4; ++m)                              \
      _Pragma("unroll") for (int n = 0; n < 4; ++n)                            \
        acc[m][n] = __builtin_amdgcn_mfma_f32_16x16x32_bf16(av[m], bv[n],      \
                                                            acc[m][n], 0, 0, 0); \
  }

  f32x4 acc[4][4] = {};

  GSTAGE(0, 0);
  GSTAGE(1, 1);

  for (int g = 0; g < 11; ++g) {
    const int kk = g * 4;
    GSTAGE(kk + 2, 2); WAITVM(8); BAR(); FENCE(); COMPUTE(0);
    GSTAGE(kk + 3, 3); WAITVM(8); BAR(); FENCE(); COMPUTE(1);
    GSTAGE(kk + 4, 0); WAITVM(8); BAR(); FENCE(); COMPUTE(2);
    GSTAGE(kk + 5, 1); WAITVM(8); BAR(); FENCE(); COMPUTE(3);
  }
  // tail: kk = 44..47
  GSTAGE(46, 2); WAITVM(8); BAR(); FENCE(); COMPUTE(0);
  GSTAGE(47, 3); WAITVM(8); BAR(); FENCE(); COMPUTE(1);
  WAITVM(4); BAR(); FENCE(); COMPUTE(2);
  WAITVM(0); BAR(); FENCE(); COMPUTE(3);
#undef GSTAGE
#undef COMPUTE

#pragma unroll
  for (int m = 0; m < 4; ++m) {
    const int p = p0 + wm * 64 + m * 16 + hi * 4;
#pragma unroll
    for (int n = 0; n < 4; ++n) {
      const int o = o0 + wn * 64 + n * 16 + row_in;
#pragma unroll
      for (int r = 0; r < 4; ++r)
        out[(size_t)((b * NCT) + p + r) * ND + o] = acc[m][n][r];
    }
  }
}

// ---------------------------------------------------------------------------
extern "C" void kernel_launch(void* const* d_in, const int* in_sizes, int n_in,
                              void* d_out, int out_size, void* d_ws, size_t ws_size,
                              hipStream_t stream) {
  const float* x = (const float*)d_in[0];
  const float* bank = (const float*)d_in[1];
  const float* tw = (const float*)d_in[2];
  float* out = (float*)d_out;

  char* ws = (char*)d_ws;
  __hip_bfloat16* Apad = (__hip_bfloat16*)ws;
  __hip_bfloat16* Wb = (__hip_bfloat16*)(ws + APAD_BYTES);
  __hip_bfloat16* bankB = (__hip_bfloat16*)(ws + APAD_BYTES + WB_BYTES);

  prep_kernel<<<256, 256, 0, stream>>>(bank, tw, Wb, bankB);
  cwt_kernel<<<256, 512, 0, stream>>>(x, bankB, Apad);
  gemm_kernel<<<512, 256, 0, stream>>>(Apad, Wb, out);
}

// Round 14
// 59.107 us; speedup vs baseline: 2.0837x; 1.0238x over previous
//
#include <hip/hip_runtime.h>
#include <hip/hip_bf16.h>

// Problem constants
#define NB 32      // batch
#define NC 8       // channels
#define NL 512     // length
#define NS 63      // scales
#define NK 1009    // max wavelet kernel length (odd)
#define NPAD 504   // (NK-1)/2
#define ND 512     // d_model
#define NCT 512    // total channels after concat = C*(1+S)
#define NROWS 514  // Apad rows per batch (circular-padded)

typedef __attribute__((ext_vector_type(4))) float f32x4;
typedef __attribute__((ext_vector_type(8))) short short8;

// Workspace layout (bytes)
#define APAD_BYTES (NB * NROWS * NL * 2)   // 16,842,752  bf16 [B][514][512]
#define WB_BYTES   (3 * ND * NL * 2)       //  1,572,864  bf16 [3][512][512]

typedef const __attribute__((address_space(1))) unsigned int* gp1_t;
typedef __attribute__((address_space(3))) unsigned int* lp3_t;
__device__ __forceinline__ void gload_lds16(const void* g, void* l) {
  __builtin_amdgcn_global_load_lds((gp1_t)g, (lp3_t)l, 16, 0, 0);
}

__device__ __forceinline__ unsigned short bf16_bits(float v) {
  return __builtin_bit_cast(unsigned short, __float2bfloat16(v));
}

#define WAITVM(N) asm volatile("s_waitcnt vmcnt(" #N ")" ::: "memory")
#define FENCE() asm volatile("" ::: "memory")
#define BAR() __builtin_amdgcn_s_barrier()
#define PRIO1() __builtin_amdgcn_s_setprio(1)
#define PRIO0() __builtin_amdgcn_s_setprio(0)

// ---------------------------------------------------------------------------
// Kernel 1: prep — Wb[k][o][l] = bf16(tw[o][l][k]); bankB[s][k] zero-padded.
// ---------------------------------------------------------------------------
__global__ __launch_bounds__(256) void prep_kernel(
    const float* __restrict__ bank, const float* __restrict__ tw,
    __hip_bfloat16* __restrict__ Wb, __hip_bfloat16* __restrict__ bankB) {
  const int idx = blockIdx.x * 256 + threadIdx.x;   // 65536 threads

  {
    int i0 = idx * 4;
    const float4* t4 = (const float4*)(tw + (size_t)i0 * 3);
    float4 a = t4[0], bq = t4[1], c4 = t4[2];
    ushort4 w0 = make_ushort4(bf16_bits(a.x), bf16_bits(a.w), bf16_bits(bq.z), bf16_bits(c4.y));
    ushort4 w1 = make_ushort4(bf16_bits(a.y), bf16_bits(bq.x), bf16_bits(bq.w), bf16_bits(c4.z));
    ushort4 w2 = make_ushort4(bf16_bits(a.z), bf16_bits(bq.y), bf16_bits(c4.x), bf16_bits(c4.w));
    *(ushort4*)(Wb + 0 * ND * NL + i0) = w0;
    *(ushort4*)(Wb + 1 * ND * NL + i0) = w1;
    *(ushort4*)(Wb + 2 * ND * NL + i0) = w2;
  }
  {
    int s = idx >> 10, k = idx & 1023;
    float v = (s < NS && k < NK) ? bank[s * NK + k] : 0.f;
    bankB[idx] = __float2bfloat16(v);
  }
}

// ---------------------------------------------------------------------------
// Kernel 2: cwt via MFMA (unchanged from R13 — measured best).
// ---------------------------------------------------------------------------
#define CPY8_STRIDE 3152   // 16*197, 197 odd -> quad spread across copies

__global__ __launch_bounds__(512) void cwt_kernel(
    const float* __restrict__ x, const __hip_bfloat16* __restrict__ bankB,
    __hip_bfloat16* __restrict__ Apad) {
  __shared__ __align__(16) char smem[8 * 16384 + 8 * CPY8_STRIDE];  // 156,288 B
  char* bankS = smem;
  char* cpy = smem + 8 * 16384;

  const int tid = threadIdx.x;
  const int bc = blockIdx.x;
  const int b = bc >> 3, c = bc & 7;
  const int w = tid >> 6, l = tid & 63;
  const int hi = l >> 4, li = l & 15;
  const int r8 = l & 7;

  const float* xrow = x + bc * NL;

  if (tid < 512) {
    __hip_bfloat16 v = __float2bfloat16(xrow[tid]);
    Apad[((size_t)(b * NROWS) + 1 + c) * NL + tid] = v;
    if (c == 0) Apad[((size_t)(b * NROWS) + 513) * NL + tid] = v;
  }

  for (int i = 0; i < 13; ++i) {
    int p = tid + i * 512;
    if (p < 6176) {
      int r_ = p / 772;
      int pe = p - r_ * 772;
      int g0 = 2 * pe;
      int i0 = g0 - 8 + r_;
      float xa = (i0 >= NPAD && i0 < NPAD + NL) ? xrow[i0 - NPAD] : 0.f;
      float xb = (i0 + 1 >= NPAD && i0 + 1 < NPAD + NL) ? xrow[i0 + 1 - NPAD] : 0.f;
      float xc = (i0 + 2 >= NPAD && i0 + 2 < NPAD + NL) ? xrow[i0 + 2 - NPAD] : 0.f;
      unsigned u = (unsigned)bf16_bits(xb - xa) | ((unsigned)bf16_bits(xc - xb) << 16);
      *(unsigned*)(cpy + r_ * CPY8_STRIDE + g0 * 2) = u;
    }
  }

#define STAGE(kt)                                                             \
  {                                                                           \
    for (int i = 0; i < 2; ++i) {                                             \
      int ck = tid + i * 512;                                                 \
      int s_ = ck >> 4, rb = ck & 15;                                         \
      int srcc = rb ^ (s_ & 7);                                               \
      gload_lds16(bankB + s_ * 1024 + (kt) * 128 + srcc * 8,                  \
                  bankS + (kt) * 16384 + ck * 16);                            \
    }                                                                         \
  }

#define AVMM(kt, ksl, m)                                                       \
  {                                                                            \
    int srow = (m) * 16 + li;                                                  \
    int chunk = ((ksl) * 4 + hi) ^ (srow & 7);                                 \
    short8 av = *(const short8*)(bankS + (kt) * 16384 + srow * 256 + chunk * 16); \
    _Pragma("unroll") for (int n = 0; n < 4; ++n)                              \
      acc[m][n] = __builtin_amdgcn_mfma_f32_16x16x32_bf16(av, bv[n],           \
                                                          acc[m][n], 0, 0, 0); \
  }

#define CCOMP(kt, M0, M1, M2, M3)                                              \
  {                                                                            \
    _Pragma("unroll") for (int ksl = 0; ksl < 4; ++ksl) {                      \
      short8 bv[4];                                                            \
      _Pragma("unroll") for (int n = 0; n < 4; ++n) {                          \
        int ebyte = 16 + 2 * (tbase + n * 16 + 8 * (li >> 3) +                 \
                              (kt) * 128 + ksl * 32 + 8 * hi);                 \
        bv[n] = *(const short8*)(cpy + r8 * CPY8_STRIDE + ebyte);              \
      }                                                                        \
      if (M0) AVMM(kt, ksl, 0);                                                \
      if (M1) AVMM(kt, ksl, 1);                                                \
      if (M2) AVMM(kt, ksl, 2);                                                \
      if (M3) AVMM(kt, ksl, 3);                                                \
    }                                                                          \
  }

  STAGE(0); STAGE(1); STAGE(2); STAGE(3);
  STAGE(4); STAGE(5); STAGE(6); STAGE(7);

  f32x4 acc[4][4] = {};
  const int tbase = w * 64;

  asm volatile("s_waitcnt vmcnt(14) lgkmcnt(0)" ::: "memory");
  BAR(); FENCE(); CCOMP(0, 0, 0, 1, 1);
  WAITVM(12); BAR(); FENCE(); CCOMP(1, 0, 1, 1, 1);
  WAITVM(10); BAR(); FENCE(); CCOMP(2, 1, 1, 1, 1);
  WAITVM(8);  BAR(); FENCE(); CCOMP(3, 1, 1, 1, 1);
  WAITVM(6);  BAR(); FENCE(); CCOMP(4, 1, 1, 1, 1);
  WAITVM(4);  BAR(); FENCE(); CCOMP(5, 0, 1, 1, 1);
  WAITVM(2);  BAR(); FENCE(); CCOMP(6, 0, 0, 1, 1);
  WAITVM(0);  BAR(); FENCE(); CCOMP(7, 0, 0, 0, 1);

#pragma unroll
  for (int m = 0; m < 4; ++m) {
#pragma unroll
    for (int rg = 0; rg < 4; ++rg) {
      int s = m * 16 + hi * 4 + rg;
      if (s >= NS) continue;
      int ch = 8 + c * NS + s;
      size_t rowbase = ((size_t)(b * NROWS) + 1 + ch) * NL;
#pragma unroll
      for (int n = 0; n < 4; ++n) {
        int t = tbase + n * 16 + li;
        float d = fabsf(acc[m][n][rg]);
        __hip_bfloat16 hv = __float2bfloat16(d);
        bool lastgrp = (w == 7 && n == 3);
        bool skip = lastgrp && (li == 15);
        bool dup = lastgrp && (li == 14);
        if (!skip) Apad[rowbase + t] = hv;
        if (dup) Apad[rowbase + 511] = hv;
        if (ch == NCT - 1) {
          size_t wrapbase = (size_t)(b * NROWS) * NL;
          if (!skip) Apad[wrapbase + t] = hv;
          if (dup) Apad[wrapbase + 511] = hv;
        }
      }
    }
  }
#undef STAGE
#undef AVMM
#undef CCOMP
}

// ---------------------------------------------------------------------------
// Kernel 3: gemm — BM=256, BN=128, BK=64 deep-phase structure.
// 512 thr (8 waves, 4M x 2N, 64x64/wave). 3 LDS buffer rotation (144 KB),
// grid 256 = 1 block/CU. Per K-tile (24): WAITVM(6); BAR; GSTAGE(kt+2);
// 2 k-slices x [8 ds_read + 16 MFMA w/ setprio]. ONE barrier + ONE wait
// per K-tile (half of before); staged L2 traffic 393->295 MB.
// Race check: GSTAGE(kt+2) writes buf (kt-1)%3, whose readers all crossed
// BAR(kt); current kt reads kt%3, next reads (kt+1)%3 — disjoint.
// T2 swizzle for 64-wide rows: chunk cs = c ^ (row&7) both sides.
// XCD decode: 8 mblks (2.1MB A) + Wb (1.5MB) per XCD < 4MB L2.
// ---------------------------------------------------------------------------
__global__ __launch_bounds__(512) void gemm_kernel(
    const __hip_bfloat16* __restrict__ Ap, const __hip_bfloat16* __restrict__ Wb,
    float* __restrict__ out) {
  __shared__ __hip_bfloat16 sA[3][256 * 64];   // 96 KB
  __shared__ __hip_bfloat16 sB[3][128 * 64];   // 48 KB

  const int tid = threadIdx.x;                 // 0..511
  const int gid = blockIdx.x;                  // 0..255
  const int idx = gid >> 3;                    // 0..31
  const int mblk = (gid & 7) * 8 + (idx & 7);  // 0..63 (XCD-local A-slab)
  const int nblk = idx >> 3;                   // 0..3
  const int b = mblk >> 1;
  const int p0 = (mblk & 1) * 256;
  const int o0 = nblk * 128;

  const int w = tid >> 6, lane = tid & 63;
  const int wm = w >> 1, wn = w & 1;           // 4M x 2N
  const int row_in = lane & 15, hi = lane >> 4;

#define GSTAGE(kt, bu)                                                         \
  {                                                                            \
    const int kap_ = (kt) >> 3;                                                \
    const int l0_ = ((kt) & 7) << 6;                                           \
    _Pragma("unroll") for (int i = 0; i < 4; ++i) {                            \
      int ck = tid + i * 512;                                                  \
      int row = ck >> 3, cg = (ck & 7) ^ (row & 7);                            \
      gload_lds16(Ap + ((b * NROWS + p0 + kap_ + row) * NL + l0_ + cg * 8),    \
                  &sA[bu][ck * 8]);                                            \
    }                                                                          \
    _Pragma("unroll") for (int i = 0; i < 2; ++i) {                            \
      int ck = tid + i * 512;                                                  \
      int row = ck >> 3, cg = (ck & 7) ^ (row & 7);                            \
      gload_lds16(Wb + ((kap_ * ND + o0 + row) * NL + l0_ + cg * 8),           \
                  &sB[bu][ck * 8]);                                            \
    }                                                                          \
  }

#define KSLICE(bu, ks)                                                         \
  {                                                                            \
    short8 av[4], bv[4];                                                       \
    _Pragma("unroll") for (int m = 0; m < 4; ++m) {                            \
      int row = wm * 64 + m * 16 + row_in;                                     \
      int cs = ((ks) * 4 + hi) ^ (row & 7);                                    \
      av[m] = *(const short8*)(&sA[bu][(row * 8 + cs) * 8]);                   \
    }                                                                          \
    _Pragma("unroll") for (int n = 0; n < 4; ++n) {                            \
      int row = wn * 64 + n * 16 + row_in;                                     \
      int cs = ((ks) * 4 + hi) ^ (row & 7);                                    \
      bv[n] = *(const short8*)(&sB[bu][(row * 8 + cs) * 8]);                   \
    }                                                                          \
    PRIO1();                                                                   \
    _Pragma("unroll") for (int m = 0; m < 4; ++m)                              \
      _Pragma("unroll") for (int n = 0; n < 4; ++n)                            \
        acc[m][n] = __builtin_amdgcn_mfma_f32_16x16x32_bf16(av[m], bv[n],      \
                                                            acc[m][n], 0, 0, 0); \
    PRIO0();                                                                   \
  }

// steady-state K-tile: drain tile kt (6 left from kt+1), barrier, prefetch
// kt+2 into the just-freed buffer, compute both k-slices of kt.
#define STEP(kt, bu, bs)                                                       \
  WAITVM(6); BAR(); FENCE();                                                   \
  GSTAGE((kt) + 2, bs);                                                        \
  KSLICE(bu, 0); KSLICE(bu, 1); FENCE();

  f32x4 acc[4][4] = {};

  GSTAGE(0, 0); GSTAGE(1, 1);

  for (int g = 0; g < 7; ++g) {     // kt = 0..20
    const int kt = g * 3;
    STEP(kt + 0, 0, 2);
    STEP(kt + 1, 1, 0);
    STEP(kt + 2, 2, 1);
  }
  // kt = 21 (stages 23), 22, 23
  STEP(21, 0, 2);
  WAITVM(6); BAR(); FENCE(); KSLICE(1, 0); KSLICE(1, 1); FENCE();
  WAITVM(0); BAR(); FENCE(); KSLICE(2, 0); KSLICE(2, 1);
#undef GSTAGE
#undef KSLICE
#undef STEP

  // epilogue: p = p0 + wm*64 + m*16 + hi*4 + r ; o = o0 + wn*64 + n*16 + row_in
#pragma unroll
  for (int m = 0; m < 4; ++m) {
    const int p = p0 + wm * 64 + m * 16 + hi * 4;
#pragma unroll
    for (int n = 0; n < 4; ++n) {
      const int o = o0 + wn * 64 + n * 16 + row_in;
#pragma unroll
      for (int r = 0; r < 4; ++r)
        out[(size_t)((b * NCT) + p + r) * ND + o] = acc[m][n][r];
    }
  }
}

// ---------------------------------------------------------------------------
extern "C" void kernel_launch(void* const* d_in, const int* in_sizes, int n_in,
                              void* d_out, int out_size, void* d_ws, size_t ws_size,
                              hipStream_t stream) {
  const float* x = (const float*)d_in[0];
  const float* bank = (const float*)d_in[1];
  const float* tw = (const float*)d_in[2];
  float* out = (float*)d_out;

  char* ws = (char*)d_ws;
  __hip_bfloat16* Apad = (__hip_bfloat16*)ws;
  __hip_bfloat16* Wb = (__hip_bfloat16*)(ws + APAD_BYTES);
  __hip_bfloat16* bankB = (__hip_bfloat16*)(ws + APAD_BYTES + WB_BYTES);

  prep_kernel<<<256, 256, 0, stream>>>(bank, tw, Wb, bankB);
  cwt_kernel<<<256, 512, 0, stream>>>(x, bankB, Apad);
  gemm_kernel<<<256, 512, 0, stream>>>(Apad, Wb, out);
}

// Round 16
// 56.764 us; speedup vs baseline: 2.1697x; 1.0413x over previous
//
#include <hip/hip_runtime.h>
#include <hip/hip_bf16.h>

// Problem constants
#define NB 32      // batch
#define NC 8       // channels
#define NL 512     // length
#define NS 63      // scales
#define NK 1009    // max wavelet kernel length (odd)
#define NPAD 504   // (NK-1)/2
#define ND 512     // d_model
#define NCT 512    // total channels after concat = C*(1+S)
#define NROWS 514  // Apad rows per batch (circular-padded)

typedef __attribute__((ext_vector_type(4))) float f32x4;
typedef __attribute__((ext_vector_type(8))) short short8;

// Workspace layout (bytes)
#define APAD_BYTES (NB * NROWS * NL * 2)   // 16,842,752  bf16 [B][514][512]
#define WB_BYTES   (3 * ND * NL * 2)       //  1,572,864  bf16 [3][512][512]

typedef const __attribute__((address_space(1))) unsigned int* gp1_t;
typedef __attribute__((address_space(3))) unsigned int* lp3_t;
__device__ __forceinline__ void gload_lds16(const void* g, void* l) {
  __builtin_amdgcn_global_load_lds((gp1_t)g, (lp3_t)l, 16, 0, 0);
}

__device__ __forceinline__ unsigned short bf16_bits(float v) {
  return __builtin_bit_cast(unsigned short, __float2bfloat16(v));
}

#define WAITVM(N) asm volatile("s_waitcnt vmcnt(" #N ")" ::: "memory")
#define FENCE() asm volatile("" ::: "memory")
#define BAR() __builtin_amdgcn_s_barrier()
#define PRIO1() __builtin_amdgcn_s_setprio(1)
#define PRIO0() __builtin_amdgcn_s_setprio(0)

// ---------------------------------------------------------------------------
// Kernel 1: prep — Wb[k][o][l] = bf16(tw[o][l][k]); bankB[s][k] zero-padded.
// ---------------------------------------------------------------------------
__global__ __launch_bounds__(256) void prep_kernel(
    const float* __restrict__ bank, const float* __restrict__ tw,
    __hip_bfloat16* __restrict__ Wb, __hip_bfloat16* __restrict__ bankB) {
  const int idx = blockIdx.x * 256 + threadIdx.x;   // 65536 threads

  {
    int i0 = idx * 4;
    const float4* t4 = (const float4*)(tw + (size_t)i0 * 3);
    float4 a = t4[0], bq = t4[1], c4 = t4[2];
    ushort4 w0 = make_ushort4(bf16_bits(a.x), bf16_bits(a.w), bf16_bits(bq.z), bf16_bits(c4.y));
    ushort4 w1 = make_ushort4(bf16_bits(a.y), bf16_bits(bq.x), bf16_bits(bq.w), bf16_bits(c4.z));
    ushort4 w2 = make_ushort4(bf16_bits(a.z), bf16_bits(bq.y), bf16_bits(c4.x), bf16_bits(c4.w));
    *(ushort4*)(Wb + 0 * ND * NL + i0) = w0;
    *(ushort4*)(Wb + 1 * ND * NL + i0) = w1;
    *(ushort4*)(Wb + 2 * ND * NL + i0) = w2;
  }
  {
    int s = idx >> 10, k = idx & 1023;
    float v = (s < NS && k < NK) ? bank[s * NK + k] : 0.f;
    bankB[idx] = __float2bfloat16(v);
  }
}

// ---------------------------------------------------------------------------
// Kernel 2: cwt via MFMA (unchanged from R13/R14 — measured best).
// ---------------------------------------------------------------------------
#define CPY8_STRIDE 3152   // 16*197, 197 odd -> quad spread across copies

__global__ __launch_bounds__(512) void cwt_kernel(
    const float* __restrict__ x, const __hip_bfloat16* __restrict__ bankB,
    __hip_bfloat16* __restrict__ Apad) {
  __shared__ __align__(16) char smem[8 * 16384 + 8 * CPY8_STRIDE];  // 156,288 B
  char* bankS = smem;
  char* cpy = smem + 8 * 16384;

  const int tid = threadIdx.x;
  const int bc = blockIdx.x;
  const int b = bc >> 3, c = bc & 7;
  const int w = tid >> 6, l = tid & 63;
  const int hi = l >> 4, li = l & 15;
  const int r8 = l & 7;

  const float* xrow = x + bc * NL;

  if (tid < 512) {
    __hip_bfloat16 v = __float2bfloat16(xrow[tid]);
    Apad[((size_t)(b * NROWS) + 1 + c) * NL + tid] = v;
    if (c == 0) Apad[((size_t)(b * NROWS) + 513) * NL + tid] = v;
  }

  for (int i = 0; i < 13; ++i) {
    int p = tid + i * 512;
    if (p < 6176) {
      int r_ = p / 772;
      int pe = p - r_ * 772;
      int g0 = 2 * pe;
      int i0 = g0 - 8 + r_;
      float xa = (i0 >= NPAD && i0 < NPAD + NL) ? xrow[i0 - NPAD] : 0.f;
      float xb = (i0 + 1 >= NPAD && i0 + 1 < NPAD + NL) ? xrow[i0 + 1 - NPAD] : 0.f;
      float xc = (i0 + 2 >= NPAD && i0 + 2 < NPAD + NL) ? xrow[i0 + 2 - NPAD] : 0.f;
      unsigned u = (unsigned)bf16_bits(xb - xa) | ((unsigned)bf16_bits(xc - xb) << 16);
      *(unsigned*)(cpy + r_ * CPY8_STRIDE + g0 * 2) = u;
    }
  }

#define STAGE(kt)                                                             \
  {                                                                           \
    for (int i = 0; i < 2; ++i) {                                             \
      int ck = tid + i * 512;                                                 \
      int s_ = ck >> 4, rb = ck & 15;                                         \
      int srcc = rb ^ (s_ & 7);                                               \
      gload_lds16(bankB + s_ * 1024 + (kt) * 128 + srcc * 8,                  \
                  bankS + (kt) * 16384 + ck * 16);                            \
    }                                                                         \
  }

#define AVMM(kt, ksl, m)                                                       \
  {                                                                            \
    int srow = (m) * 16 + li;                                                  \
    int chunk = ((ksl) * 4 + hi) ^ (srow & 7);                                 \
    short8 av = *(const short8*)(bankS + (kt) * 16384 + srow * 256 + chunk * 16); \
    _Pragma("unroll") for (int n = 0; n < 4; ++n)                              \
      acc[m][n] = __builtin_amdgcn_mfma_f32_16x16x32_bf16(av, bv[n],           \
                                                          acc[m][n], 0, 0, 0); \
  }

#define CCOMP(kt, M0, M1, M2, M3)                                              \
  {                                                                            \
    _Pragma("unroll") for (int ksl = 0; ksl < 4; ++ksl) {                      \
      short8 bv[4];                                                            \
      _Pragma("unroll") for (int n = 0; n < 4; ++n) {                          \
        int ebyte = 16 + 2 * (tbase + n * 16 + 8 * (li >> 3) +                 \
                              (kt) * 128 + ksl * 32 + 8 * hi);                 \
        bv[n] = *(const short8*)(cpy + r8 * CPY8_STRIDE + ebyte);              \
      }                                                                        \
      if (M0) AVMM(kt, ksl, 0);                                                \
      if (M1) AVMM(kt, ksl, 1);                                                \
      if (M2) AVMM(kt, ksl, 2);                                                \
      if (M3) AVMM(kt, ksl, 3);                                                \
    }                                                                          \
  }

  STAGE(0); STAGE(1); STAGE(2); STAGE(3);
  STAGE(4); STAGE(5); STAGE(6); STAGE(7);

  f32x4 acc[4][4] = {};
  const int tbase = w * 64;

  asm volatile("s_waitcnt vmcnt(14) lgkmcnt(0)" ::: "memory");
  BAR(); FENCE(); CCOMP(0, 0, 0, 1, 1);
  WAITVM(12); BAR(); FENCE(); CCOMP(1, 0, 1, 1, 1);
  WAITVM(10); BAR(); FENCE(); CCOMP(2, 1, 1, 1, 1);
  WAITVM(8);  BAR(); FENCE(); CCOMP(3, 1, 1, 1, 1);
  WAITVM(6);  BAR(); FENCE(); CCOMP(4, 1, 1, 1, 1);
  WAITVM(4);  BAR(); FENCE(); CCOMP(5, 0, 1, 1, 1);
  WAITVM(2);  BAR(); FENCE(); CCOMP(6, 0, 0, 1, 1);
  WAITVM(0);  BAR(); FENCE(); CCOMP(7, 0, 0, 0, 1);

#pragma unroll
  for (int m = 0; m < 4; ++m) {
#pragma unroll
    for (int rg = 0; rg < 4; ++rg) {
      int s = m * 16 + hi * 4 + rg;
      if (s >= NS) continue;
      int ch = 8 + c * NS + s;
      size_t rowbase = ((size_t)(b * NROWS) + 1 + ch) * NL;
#pragma unroll
      for (int n = 0; n < 4; ++n) {
        int t = tbase + n * 16 + li;
        float d = fabsf(acc[m][n][rg]);
        __hip_bfloat16 hv = __float2bfloat16(d);
        bool lastgrp = (w == 7 && n == 3);
        bool skip = lastgrp && (li == 15);
        bool dup = lastgrp && (li == 14);
        if (!skip) Apad[rowbase + t] = hv;
        if (dup) Apad[rowbase + 511] = hv;
        if (ch == NCT - 1) {
          size_t wrapbase = (size_t)(b * NROWS) * NL;
          if (!skip) Apad[wrapbase + t] = hv;
          if (dup) Apad[wrapbase + 511] = hv;
        }
      }
    }
  }
#undef STAGE
#undef AVMM
#undef CCOMP
}

// ---------------------------------------------------------------------------
// Kernel 3: gemm — BM=256, BN=128, BK=64, 8 waves (4Mx2N), 3-buf rotation.
// R14's PROVEN sync structure: per K-tile WAITVM(6); BAR(); then all reads
// and stage-issues strictly AFTER the barrier (R15's pre-barrier ds_read
// raced — WAITVM is per-wave and cannot substitute for the barrier).
// Residual fine-interleave: the 6 staging loads split in halves between the
// two k-slice MFMA clusters. setprio around MFMA. T2 swizzle cs=c^(row&7);
// T1 XCD decode (8 mblks A 2.1MB + Wb 1.5MB per XCD < 4MB L2).
// ---------------------------------------------------------------------------
__global__ __launch_bounds__(512) void gemm_kernel(
    const __hip_bfloat16* __restrict__ Ap, const __hip_bfloat16* __restrict__ Wb,
    float* __restrict__ out) {
  __shared__ __hip_bfloat16 sA[3][256 * 64];   // 96 KB
  __shared__ __hip_bfloat16 sB[3][128 * 64];   // 48 KB

  const int tid = threadIdx.x;                 // 0..511
  const int gid = blockIdx.x;                  // 0..255
  const int idx = gid >> 3;                    // 0..31
  const int mblk = (gid & 7) * 8 + (idx & 7);  // 0..63 (XCD-local A-slab)
  const int nblk = idx >> 3;                   // 0..3
  const int b = mblk >> 1;
  const int p0 = (mblk & 1) * 256;
  const int o0 = nblk * 128;

  const int w = tid >> 6, lane = tid & 63;
  const int wm = w >> 1, wn = w & 1;           // 4M x 2N
  const int row_in = lane & 15, hi = lane >> 4;

#define GSTAGE_H0(kt, bu)                                                      \
  {                                                                            \
    const int kap_ = (kt) >> 3;                                                \
    const int l0_ = ((kt) & 7) << 6;                                           \
    _Pragma("unroll") for (int i = 0; i < 2; ++i) {                            \
      int ck = tid + i * 512;                                                  \
      int row = ck >> 3, cg = (ck & 7) ^ (row & 7);                            \
      gload_lds16(Ap + ((b * NROWS + p0 + kap_ + row) * NL + l0_ + cg * 8),    \
                  &sA[bu][ck * 8]);                                            \
    }                                                                          \
    {                                                                          \
      int ck = tid;                                                            \
      int row = ck >> 3, cg = (ck & 7) ^ (row & 7);                            \
      gload_lds16(Wb + ((kap_ * ND + o0 + row) * NL + l0_ + cg * 8),           \
                  &sB[bu][ck * 8]);                                            \
    }                                                                          \
  }

#define GSTAGE_H1(kt, bu)                                                      \
  {                                                                            \
    const int kap_ = (kt) >> 3;                                                \
    const int l0_ = ((kt) & 7) << 6;                                           \
    _Pragma("unroll") for (int i = 2; i < 4; ++i) {                            \
      int ck = tid + i * 512;                                                  \
      int row = ck >> 3, cg = (ck & 7) ^ (row & 7);                            \
      gload_lds16(Ap + ((b * NROWS + p0 + kap_ + row) * NL + l0_ + cg * 8),    \
                  &sA[bu][ck * 8]);                                            \
    }                                                                          \
    {                                                                          \
      int ck = tid + 512;                                                      \
      int row = ck >> 3, cg = (ck & 7) ^ (row & 7);                            \
      gload_lds16(Wb + ((kap_ * ND + o0 + row) * NL + l0_ + cg * 8),           \
                  &sB[bu][ck * 8]);                                            \
    }                                                                          \
  }

// one k-slice: ds_read frags (post-barrier, safe) ; issue half-stage ; MFMA
#define SLICE(bu, ks, STG)                                                     \
  {                                                                            \
    short8 av[4], bv[4];                                                       \
    _Pragma("unroll") for (int m = 0; m < 4; ++m) {                            \
      int row = wm * 64 + m * 16 + row_in;                                     \
      int cs = ((ks) * 4 + hi) ^ (row & 7);                                    \
      av[m] = *(const short8*)(&sA[bu][(row * 8 + cs) * 8]);                   \
    }                                                                          \
    _Pragma("unroll") for (int n = 0; n < 4; ++n) {                            \
      int row = wn * 64 + n * 16 + row_in;                                     \
      int cs = ((ks) * 4 + hi) ^ (row & 7);                                    \
      bv[n] = *(const short8*)(&sB[bu][(row * 8 + cs) * 8]);                   \
    }                                                                          \
    STG;                                                                       \
    PRIO1();                                                                   \
    _Pragma("unroll") for (int m = 0; m < 4; ++m)                              \
      _Pragma("unroll") for (int n = 0; n < 4; ++n)                            \
        acc[m][n] = __builtin_amdgcn_mfma_f32_16x16x32_bf16(av[m], bv[n],      \
                                                            acc[m][n], 0, 0, 0); \
    PRIO0();                                                                   \
  }

#define STEP(kt, bu, bs)                                                       \
  WAITVM(6); BAR(); FENCE();                                                   \
  SLICE(bu, 0, GSTAGE_H0((kt) + 2, bs));                                       \
  SLICE(bu, 1, GSTAGE_H1((kt) + 2, bs));                                       \
  FENCE();

  f32x4 acc[4][4] = {};

  GSTAGE_H0(0, 0); GSTAGE_H1(0, 0);
  GSTAGE_H0(1, 1); GSTAGE_H1(1, 1);

  for (int g = 0; g < 7; ++g) {     // kt = 0..20
    const int kt = g * 3;
    STEP(kt + 0, 0, 2);
    STEP(kt + 1, 1, 0);
    STEP(kt + 2, 2, 1);
  }
  // kt = 21 (stages tile 23), 22, 23
  STEP(21, 0, 2);
  WAITVM(6); BAR(); FENCE(); SLICE(1, 0, (void)0); SLICE(1, 1, (void)0); FENCE();
  WAITVM(0); BAR(); FENCE(); SLICE(2, 0, (void)0); SLICE(2, 1, (void)0);
#undef GSTAGE_H0
#undef GSTAGE_H1
#undef SLICE
#undef STEP

  // epilogue: p = p0 + wm*64 + m*16 + hi*4 + r ; o = o0 + wn*64 + n*16 + row_in
#pragma unroll
  for (int m = 0; m < 4; ++m) {
    const int p = p0 + wm * 64 + m * 16 + hi * 4;
#pragma unroll
    for (int n = 0; n < 4; ++n) {
      const int o = o0 + wn * 64 + n * 16 + row_in;
#pragma unroll
      for (int r = 0; r < 4; ++r)
        out[(size_t)((b * NCT) + p + r) * ND + o] = acc[m][n][r];
    }
  }
}

// ---------------------------------------------------------------------------
extern "C" void kernel_launch(void* const* d_in, const int* in_sizes, int n_in,
                              void* d_out, int out_size, void* d_ws, size_t ws_size,
                              hipStream_t stream) {
  const float* x = (const float*)d_in[0];
  const float* bank = (const float*)d_in[1];
  const float* tw = (const float*)d_in[2];
  float* out = (float*)d_out;

  char* ws = (char*)d_ws;
  __hip_bfloat16* Apad = (__hip_bfloat16*)ws;
  __hip_bfloat16* Wb = (__hip_bfloat16*)(ws + APAD_BYTES);
  __hip_bfloat16* bankB = (__hip_bfloat16*)(ws + APAD_BYTES + WB_BYTES);

  prep_kernel<<<256, 256, 0, stream>>>(bank, tw, Wb, bankB);
  cwt_kernel<<<256, 512, 0, stream>>>(x, bankB, Apad);
  gemm_kernel<<<256, 512, 0, stream>>>(Apad, Wb, out);
}